// Round 3
// baseline (899.893 us; speedup 1.0000x reference)
//
#include <hip/hip_runtime.h>
#include <hip/hip_bf16.h>
#include <math.h>

#define H 768
#define B 256
#define T 100

typedef __attribute__((ext_vector_type(8))) short short8;
typedef __attribute__((ext_vector_type(4))) float f32x4;
typedef unsigned long long u64;

static __device__ __forceinline__ float sigm(float x) {
    return 1.0f / (1.0f + __expf(-x));
}
static __device__ __forceinline__ float tanh_fast(float x) {
    return 1.0f - 2.0f / (__expf(2.0f * x) + 1.0f);
}

// ---------------- fused prep (single dispatch) ----------------
// grid dim3(3, 9808), block 256:
//   y <  3072 : weight row y  (Wc, Wcat, bias)
//   y <  3152 : Wp row (y-3072), zero-padded beyond 72
//   y <  3408 : A0 batch row (y-3152)
//   y <  9808 : sig zero chunk (y-3408): 6400 rows x 768 u64 = 39.3 MB
//               (+ block (3408,0) zeroes the 256 step-flags)
__global__ void prep_all(const float* __restrict__ src, const float* __restrict__ h0,
                         const float* __restrict__ Wih, const float* __restrict__ Whh,
                         const float* __restrict__ bih, const float* __restrict__ bhh,
                         const float* __restrict__ Wpost,
                         __hip_bfloat16* __restrict__ Wc,    // 3072 x 768 (Wih+Whh)
                         __hip_bfloat16* __restrict__ Wcat,  // 3072 x 1536 [Wih|Whh]
                         float* __restrict__ bias,           // 3072
                         __hip_bfloat16* __restrict__ Wp,    // 80 x 768
                         __hip_bfloat16* __restrict__ A0,    // 256 x 1536 [x0|h0]
                         u64* __restrict__ sig64,            // T*B*192 u64, zeroed
                         unsigned* __restrict__ flags)       // 256 step flags
{
    const int bx = blockIdx.x;
    const int y  = blockIdx.y;
    const int k  = bx * 256 + threadIdx.x;
    if (y < 3072) {
        float a = Wih[y * H + k];
        float b = Whh[y * H + k];
        Wc[y * H + k] = __float2bfloat16(a + b);
        Wcat[y * 1536 + k] = __float2bfloat16(a);
        Wcat[y * 1536 + H + k] = __float2bfloat16(b);
        if (bx == 0 && threadIdx.x == 0) bias[y] = bih[y] + bhh[y];
    } else if (y < 3152) {
        int r = y - 3072;
        Wp[r * H + k] = (r < 72) ? __float2bfloat16(Wpost[r * H + k])
                                 : __float2bfloat16(0.0f);
    } else if (y < 3408) {
        int b = y - 3152;
        A0[b * 1536 + k] = __float2bfloat16(src[(b * 16 + 15) * H + k]);  // src[:, -1]
        A0[b * 1536 + H + k] = __float2bfloat16(h0[b * H + k]);
    } else {
        sig64[(size_t)(y - 3408) * 768 + k] = 0ull;
        if (y == 3408 && bx == 0) flags[threadIdx.x] = 0u;
    }
}

// ---------------- persistent recurrence: steps 0..99 ----------------
// R9 skeleton: 256 blocks (16 mtg x 16 jg) x 768 threads (12 waves = 3 jt x
// 4 gates), 1 gate/wave, 24 pinned short8 (sound grouped-asm loads).
// R14: agent-scope publish (store IS the signal), proven 354us.
// R17: flag-gated exchange replaces the per-word poll storm.
//   R14's cost was poll CONGESTION: 768 thr x 256 blk spin-loading 3072 u64
//   words/step against the MALL (~480 GB/s of poll traffic, FETCH 170MB),
//   congesting the fabric the h-stores themselves need. R16 proved the local
//   L2 cannot help (agent stores bypass all L2s; sc0 probes hit stale lines).
//   Now: producer drains its stores (per-thread vmcnt(0) + barrier) then
//   release-stores flags[mtg*16+jg]=t+1. Consumer polls its group's 16 flags
//   (ONE 64B line, lanes 0..15 of wave 0) then batch-loads the whole ready
//   tile. sig stays zero-init + inverted-nonzero encoded and the sig_ok retry
//   remains as fallback -> the flag is an optimization gate only; worst case
//   degrades to R14 behavior, never corruption.
#define LDS_H_STRIDE  772    // shorts; 8B-aligned rows, low conflicts (R9-measured)
#define LDS_T0_STRIDE 1540   // shorts
#define XCH_STRIDE    17     // 16 + 1 pad floats
#define GUARD_MAX     (1 << 22)

#define LDW8(n0,n1,n2,n3,n4,n5,n6,n7, p) \
    asm volatile("global_load_dwordx4 %0, %8, off\n\t" \
                 "global_load_dwordx4 %1, %8, off offset:64\n\t" \
                 "global_load_dwordx4 %2, %8, off offset:128\n\t" \
                 "global_load_dwordx4 %3, %8, off offset:192\n\t" \
                 "global_load_dwordx4 %4, %8, off offset:256\n\t" \
                 "global_load_dwordx4 %5, %8, off offset:320\n\t" \
                 "global_load_dwordx4 %6, %8, off offset:384\n\t" \
                 "global_load_dwordx4 %7, %8, off offset:448\n\t" \
                 "s_waitcnt vmcnt(0)" \
                 : "=&v"(n0),"=&v"(n1),"=&v"(n2),"=&v"(n3), \
                   "=&v"(n4),"=&v"(n5),"=&v"(n6),"=&v"(n7) \
                 : "v"(p))

// 4 batched agent-scope (sc1: L1/L2-bypass, MALL-coherent) u64 loads, one wait.
#define LDP4_AG(x0,x1,x2,x3, p0,p1,p2,p3) \
    asm volatile("global_load_dwordx2 %0, %4, off sc1\n\t" \
                 "global_load_dwordx2 %1, %5, off sc1\n\t" \
                 "global_load_dwordx2 %2, %6, off sc1\n\t" \
                 "global_load_dwordx2 %3, %7, off sc1\n\t" \
                 "s_waitcnt vmcnt(0)" \
                 : "=&v"(x0),"=&v"(x1),"=&v"(x2),"=&v"(x3) \
                 : "v"(p0),"v"(p1),"v"(p2),"v"(p3))

#define AG_LD(p) __hip_atomic_load((p), __ATOMIC_RELAXED, __HIP_MEMORY_SCOPE_AGENT)

#define KSTEP(nm, idx) { \
    short8 a_ = *(const short8*)(&lds_h[col * LDS_H_STRIDE + (idx) * 32 + quad * 8]); \
    acc = __builtin_amdgcn_mfma_f32_16x16x32_bf16(a_, nm, acc, 0, 0, 0); }

static __device__ __forceinline__ bool sig_ok(u64 x) {
    return (unsigned short)x && (unsigned short)(x >> 16) &&
           (unsigned short)(x >> 32) && (unsigned short)(x >> 48);
}

__global__ __launch_bounds__(768, 3) void lstm_persist(
    const __hip_bfloat16* __restrict__ Wc,    // 3072 x 768 bf16 (Wih+Whh)
    const __hip_bfloat16* __restrict__ Wcat,  // 3072 x 1536 bf16 [Wih|Whh]
    const float* __restrict__ bias,           // 3072
    const float* __restrict__ c0in,           // B x H fp32
    const __hip_bfloat16* __restrict__ A0,    // 256 x 1536 [x0|h0]
    unsigned* sig,                            // T x B x 384 u32 (~bf16 pairs), zeroed
    unsigned* flags)                          // 256 per-block step flags
{
    const int mtg  = blockIdx.x >> 4;    // batch group 0..15 (16 batches)
    const int jg   = blockIdx.x & 15;    // j group 0..15 (48 j values)
    const int tid  = threadIdx.x;
    const int lane = tid & 63;
    const int wave = tid >> 6;           // 0..11
    const int col  = lane & 15;
    const int quad = lane >> 4;
    const int jt_l = wave >> 2;          // 0..2  local j-tile
    const int gate = wave & 3;           // 0..3  (i,f,g,o)
    const int j    = jg * 48 + jt_l * 16 + col;   // this wave's j column

    __shared__ short lds_h[16 * LDS_T0_STRIDE];   // 49280 B (t0 tile; t>=1 stride 772)
    __shared__ float xch[12 * 16 * XCH_STRIDE];   // 13056 B gate exchange

    // ---- pin resident weight slice (Wc) in regs: 24 x short8 (sound asm) ----
    const short* wptr = (const short*)Wc + (size_t)(gate * H + j) * H + quad * 8;
    short8 w00,w01,w02,w03,w04,w05,w06,w07,w08,w09,w10,w11,
           w12,w13,w14,w15,w16,w17,w18,w19,w20,w21,w22,w23;
    LDW8(w00,w01,w02,w03,w04,w05,w06,w07, wptr);
    LDW8(w08,w09,w10,w11,w12,w13,w14,w15, wptr + 256);
    LDW8(w16,w17,w18,w19,w20,w21,w22,w23, wptr + 512);

    // ---- cell-role state (threads 0..383: two adjacent-j cells each) ----
    const int p    = tid;                 // pair id if < 384 (waves 0..5)
    const int bb   = p / 24;              // local batch 0..15
    const int jp   = p % 24;
    const int jloc = jp * 2;              // local j 0..46 (even)
    const int cjt  = jloc >> 4;           // j-tile of the pair
    const int jcol = jloc & 15;
    const int bglob = mtg * 16 + bb;
    const int jglob = jg * 48 + jloc;
    float c0v = 0.f, c1v = 0.f;
    float bi0=0,bi1=0,bf0=0,bf1=0,bg0=0,bg1=0,bo0=0,bo1=0;
    if (p < 384) {
        c0v = c0in[(size_t)bglob * H + jglob];
        c1v = c0in[(size_t)bglob * H + jglob + 1];
        bi0 = bias[0*H + jglob]; bi1 = bias[0*H + jglob + 1];
        bf0 = bias[1*H + jglob]; bf1 = bias[1*H + jglob + 1];
        bg0 = bias[2*H + jglob]; bg1 = bias[2*H + jglob + 1];
        bo0 = bias[3*H + jglob]; bo1 = bias[3*H + jglob + 1];
    }

    const u64* sig64c = (const u64*)sig;
    const int r0  = tid / 192;    // staging row base 0..3
    const int wrd = tid % 192;    // u64 word within row

    for (int t = 0; t < T; ++t) {
        f32x4 acc = {0.f, 0.f, 0.f, 0.f};

        if (t == 0) {
            // ---- stage A0[16 rows][1536] -> LDS ----
            const u64* a8 = (const u64*)((const short*)A0 + (size_t)(mtg * 16) * 1536);
#pragma unroll
            for (int i = 0; i < 8; ++i) {
                int idx = tid + i * 768;      // 0..6143 (16 rows x 384 u64)
                int br  = idx / 384;
                int ch  = idx % 384;
                *(u64*)&lds_h[br * LDS_T0_STRIDE + ch * 4] = a8[(size_t)br * 384 + ch];
            }
            __syncthreads();   // (B)

            // ---- K=1536 GEMM streaming Wcat (one-time) ----
            const short* wq = (const short*)Wcat + (size_t)(gate * H + j) * 1536 + quad * 8;
            for (int kk = 0; kk < 48; ++kk) {
                short8 a_ = *(const short8*)(&lds_h[col * LDS_T0_STRIDE + kk * 32 + quad * 8]);
                short8 b_ = *(const short8*)(wq + kk * 32);
                acc = __builtin_amdgcn_mfma_f32_16x16x32_bf16(a_, b_, acc, 0, 0, 0);
            }
        } else {
            // ---- flag gate: group's 16 producer flags live in ONE 64B line ----
            if (tid < 16) {
                const unsigned tgt = (unsigned)t;
                unsigned v = AG_LD(&flags[mtg * 16 + tid]);
                int fg = 0;
                while (v < tgt && ++fg < GUARD_MAX) {
                    __builtin_amdgcn_s_sleep(1);
                    v = AG_LD(&flags[mtg * 16 + tid]);
                }
            }
            __syncthreads();   // (A) tile t-1 fully published (modulo drain leak)

            // ---- batched guaranteed-ready tile load: 4 owned u64 words ----
            const u64* hb = sig64c + ((size_t)(t - 1) * B + (size_t)(mtg * 16)) * 192 + wrd;
            const u64* q0 = hb + (size_t)(r0     ) * 192;
            const u64* q1 = hb + (size_t)(r0 +  4) * 192;
            const u64* q2 = hb + (size_t)(r0 +  8) * 192;
            const u64* q3 = hb + (size_t)(r0 + 12) * 192;
            u64 x0, x1, x2, x3;
            LDP4_AG(x0, x1, x2, x3, q0, q1, q2, q3);
            unsigned pending = 0xFu;
            if (sig_ok(x0)) { *(u64*)&lds_h[(r0     ) * LDS_H_STRIDE + wrd * 4] = ~x0; pending &= ~1u; }
            if (sig_ok(x1)) { *(u64*)&lds_h[(r0 +  4) * LDS_H_STRIDE + wrd * 4] = ~x1; pending &= ~2u; }
            if (sig_ok(x2)) { *(u64*)&lds_h[(r0 +  8) * LDS_H_STRIDE + wrd * 4] = ~x2; pending &= ~4u; }
            if (sig_ok(x3)) { *(u64*)&lds_h[(r0 + 12) * LDS_H_STRIDE + wrd * 4] = ~x3; pending &= ~8u; }
            // fallback retry (expected: never taken; flag is an optimization gate)
            int guard = 0;
            while (pending && ++guard < GUARD_MAX) {
                __builtin_amdgcn_s_sleep(4);
                if (pending & 1u) { x0 = AG_LD(q0);
                    if (sig_ok(x0)) { *(u64*)&lds_h[(r0     ) * LDS_H_STRIDE + wrd * 4] = ~x0; pending &= ~1u; } }
                if (pending & 2u) { x1 = AG_LD(q1);
                    if (sig_ok(x1)) { *(u64*)&lds_h[(r0 +  4) * LDS_H_STRIDE + wrd * 4] = ~x1; pending &= ~2u; } }
                if (pending & 4u) { x2 = AG_LD(q2);
                    if (sig_ok(x2)) { *(u64*)&lds_h[(r0 +  8) * LDS_H_STRIDE + wrd * 4] = ~x2; pending &= ~4u; } }
                if (pending & 8u) { x3 = AG_LD(q3);
                    if (sig_ok(x3)) { *(u64*)&lds_h[(r0 + 12) * LDS_H_STRIDE + wrd * 4] = ~x3; pending &= ~8u; } }
            }
            __syncthreads();   // (B) lds_h ready

            // ---- K=768 GEMM vs pinned weights ----
            KSTEP(w00,0)  KSTEP(w01,1)  KSTEP(w02,2)  KSTEP(w03,3)
            KSTEP(w04,4)  KSTEP(w05,5)  KSTEP(w06,6)  KSTEP(w07,7)
            KSTEP(w08,8)  KSTEP(w09,9)  KSTEP(w10,10) KSTEP(w11,11)
            KSTEP(w12,12) KSTEP(w13,13) KSTEP(w14,14) KSTEP(w15,15)
            KSTEP(w16,16) KSTEP(w17,17) KSTEP(w18,18) KSTEP(w19,19)
            KSTEP(w20,20) KSTEP(w21,21) KSTEP(w22,22) KSTEP(w23,23)
        }

        // ---- exchange gate tiles through LDS ----
        float* xw = &xch[(size_t)wave * 16 * XCH_STRIDE];
#pragma unroll
        for (int r = 0; r < 4; ++r)
            xw[(quad * 4 + r) * XCH_STRIDE + col] = acc[r];
        __syncthreads();   // (C) xch ready; all lds_h reads of this step done

        // ---- cell update + inverted-bf16 publish (agent store, MALL-visible) ----
        if (p < 384) {
            const float* xg = &xch[(size_t)(cjt * 4) * 16 * XCH_STRIDE + bb * XCH_STRIDE + jcol];
            const int gs = 16 * XCH_STRIDE;
            float i0 = xg[0*gs] + bi0, i1 = xg[0*gs + 1] + bi1;
            float f0 = xg[1*gs] + bf0, f1 = xg[1*gs + 1] + bf1;
            float g0 = xg[2*gs] + bg0, g1 = xg[2*gs + 1] + bg1;
            float o0 = xg[3*gs] + bo0, o1 = xg[3*gs + 1] + bo1;
            float cn0 = sigm(f0) * c0v + sigm(i0) * tanh_fast(g0);
            float cn1 = sigm(f1) * c1v + sigm(i1) * tanh_fast(g1);
            c0v = cn0; c1v = cn1;
            __hip_bfloat16 h0b = __float2bfloat16(sigm(o0) * tanh_fast(cn0));
            __hip_bfloat16 h1b = __float2bfloat16(sigm(o1) * tanh_fast(cn1));
            unsigned lo = (unsigned)(unsigned short)~(*(unsigned short*)&h0b);  // nonzero
            unsigned hi = (unsigned)(unsigned short)~(*(unsigned short*)&h1b);  // nonzero
            __hip_atomic_store(&sig[((size_t)t * B + bglob) * 384 + (jglob >> 1)],
                               lo | (hi << 16),
                               __ATOMIC_RELAXED, __HIP_MEMORY_SCOPE_AGENT);
        }
        // drain every thread's publish stores before the flag can be raised
        asm volatile("s_waitcnt vmcnt(0)" ::: "memory");
        __syncthreads();   // (D) all 384 publishes of this block drained

        if (tid == 0)
            __hip_atomic_store(&flags[mtg * 16 + jg], (unsigned)(t + 1),
                               __ATOMIC_RELEASE, __HIP_MEMORY_SCOPE_AGENT);
    }
}

// ---------------- post projection (reads inverted sig) ----------------
__global__ __launch_bounds__(64) void proj(
    const short* __restrict__ Hs,            // (T*B) x 768 inverted bf16
    const __hip_bfloat16* __restrict__ Wp,   // 80 x H (padded bf16)
    const float* __restrict__ bpost,         // 72
    float* __restrict__ out)                 // B x T x 72
{
    const int mt = blockIdx.x;
    const int lane = threadIdx.x;
    const int col = lane & 15;
    const int quad = lane >> 4;

    const short* Ap = Hs + (size_t)(mt * 16 + col) * H + quad * 8;
    const short* Wb = (const short*)Wp;

    f32x4 acc[5];
#pragma unroll
    for (int nt = 0; nt < 5; ++nt) acc[nt] = (f32x4){0.f, 0.f, 0.f, 0.f};

    for (int k = 0; k < H; k += 32) {
        short8 a = ~(*(const short8*)(Ap + k));   // un-invert
#pragma unroll
        for (int nt = 0; nt < 5; ++nt) {
            short8 b = *(const short8*)(Wb + (size_t)(nt * 16 + col) * H + quad * 8 + k);
            acc[nt] = __builtin_amdgcn_mfma_f32_16x16x32_bf16(a, b, acc[nt], 0, 0, 0);
        }
    }

#pragma unroll
    for (int nt = 0; nt < 5; ++nt) {
        const int o = nt * 16 + col;
        if (o < 72) {
            const float bb = bpost[o];
#pragma unroll
            for (int r = 0; r < 4; ++r) {
                const int m = mt * 16 + quad * 4 + r;
                const int t = m >> 8;        // row = t*256 + b
                const int b = m & 255;
                out[((size_t)b * T + t) * 72 + o] = acc[nt][r] + bb;
            }
        }
    }
}

// ---------------- launch ----------------

extern "C" void kernel_launch(void* const* d_in, const int* in_sizes, int n_in,
                              void* d_out, int out_size, void* d_ws, size_t ws_size,
                              hipStream_t stream) {
    const float* src   = (const float*)d_in[0];
    const float* h0    = (const float*)d_in[2];
    const float* c0    = (const float*)d_in[3];
    const float* Wih   = (const float*)d_in[4];
    const float* Whh   = (const float*)d_in[5];
    const float* bih   = (const float*)d_in[6];
    const float* bhh   = (const float*)d_in[7];
    const float* Wpost = (const float*)d_in[8];
    const float* bpost = (const float*)d_in[9];
    float* out = (float*)d_out;

    char* ws = (char*)d_ws;
    __hip_bfloat16* Wcat = (__hip_bfloat16*)(ws + 0);          //  9,437,184 B
    __hip_bfloat16* Wc   = (__hip_bfloat16*)(ws + 9437184);    //  4,718,592 B
    float*          bias = (float*)(ws + 14155776);            //     12,288 B
    __hip_bfloat16* Wp   = (__hip_bfloat16*)(ws + 14168064);   //    122,880 B
    __hip_bfloat16* A0   = (__hip_bfloat16*)(ws + 14290944);   //    786,432 B
    unsigned*       flags= (unsigned*)(ws + 15077376);         //      1,024 B (hole)
    unsigned*       sig  = (unsigned*)(ws + 15863808);         // 39,321,600 B

    // all prep (weights, Wp, A0, sig zero, flags zero) in one dispatch
    prep_all<<<dim3(3, 9808), 256, 0, stream>>>(src, h0, Wih, Whh, bih, bhh, Wpost,
                                                Wc, Wcat, bias, Wp, A0, (u64*)sig, flags);

    // steps 0..99 in one persistent kernel (flag-gated exchange)
    lstm_persist<<<256, 768, 0, stream>>>(Wc, Wcat, bias, c0, A0, sig, flags);

    proj<<<1600, 64, 0, stream>>>((const short*)sig, Wp, bpost, out);
}

// Round 4
// 492.909 us; speedup vs baseline: 1.8257x; 1.8257x over previous
//
#include <hip/hip_runtime.h>
#include <hip/hip_bf16.h>
#include <math.h>

#define H 768
#define B 256
#define T 100

typedef __attribute__((ext_vector_type(8))) short short8;
typedef __attribute__((ext_vector_type(4))) float f32x4;
typedef unsigned long long u64;

static __device__ __forceinline__ float sigm(float x) {
    return 1.0f / (1.0f + __expf(-x));
}
static __device__ __forceinline__ float tanh_fast(float x) {
    return 1.0f - 2.0f / (__expf(2.0f * x) + 1.0f);
}

// ---------------- fused prep (single dispatch) ----------------
// grid dim3(3, 9808), block 256:
//   y <  3072 : weight row y  (Wc, Wcat, bias)
//   y <  3152 : Wp row (y-3072), zero-padded beyond 72
//   y <  3408 : A0 batch row (y-3152)
//   y <  9808 : sig zero chunk (y-3408): 6400 rows x 768 u64 = 39.3 MB
__global__ void prep_all(const float* __restrict__ src, const float* __restrict__ h0,
                         const float* __restrict__ Wih, const float* __restrict__ Whh,
                         const float* __restrict__ bih, const float* __restrict__ bhh,
                         const float* __restrict__ Wpost,
                         __hip_bfloat16* __restrict__ Wc,    // 3072 x 768 (Wih+Whh)
                         __hip_bfloat16* __restrict__ Wcat,  // 3072 x 1536 [Wih|Whh]
                         float* __restrict__ bias,           // 3072
                         __hip_bfloat16* __restrict__ Wp,    // 80 x 768
                         __hip_bfloat16* __restrict__ A0,    // 256 x 1536 [x0|h0]
                         u64* __restrict__ sig64)            // T*B*192 u64, zeroed
{
    const int bx = blockIdx.x;
    const int y  = blockIdx.y;
    const int k  = bx * 256 + threadIdx.x;
    if (y < 3072) {
        float a = Wih[y * H + k];
        float b = Whh[y * H + k];
        Wc[y * H + k] = __float2bfloat16(a + b);
        Wcat[y * 1536 + k] = __float2bfloat16(a);
        Wcat[y * 1536 + H + k] = __float2bfloat16(b);
        if (bx == 0 && threadIdx.x == 0) bias[y] = bih[y] + bhh[y];
    } else if (y < 3152) {
        int r = y - 3072;
        Wp[r * H + k] = (r < 72) ? __float2bfloat16(Wpost[r * H + k])
                                 : __float2bfloat16(0.0f);
    } else if (y < 3408) {
        int b = y - 3152;
        A0[b * 1536 + k] = __float2bfloat16(src[(b * 16 + 15) * H + k]);  // src[:, -1]
        A0[b * 1536 + H + k] = __float2bfloat16(h0[b * H + k]);
    } else {
        sig64[(size_t)(y - 3408) * 768 + k] = 0ull;
    }
}

// ---------------- persistent recurrence: steps 0..99 ----------------
// R14 core VERBATIM (proven 354us): 256 blocks (16 mtg x 16 jg) x 768 threads,
// 1 gate/wave, 24 pinned short8, batched poll + (D) barrier throttle +
// s_sleep(4). R16/R17 lessons: agent stores bypass ALL L2s (no L2-coherent
// exchange exists); poll-is-the-load overlap beats flag-then-load; per-step
// release fences are catastrophic. DO NOT TOUCH THE EXCHANGE.
// R18: proj folded into the tail. Tiles t<=98 of this group are
// MALL-visible-guaranteed (this block's own step t+1 polls saw every word
// nonzero; agent stores are monotone visible). Tile 99 is staged by one extra
// run of the proven poll block into lds_h. Fold reads of sig use sc1 (agent)
// loads ONLY: plain loads could hit stale zero lines parked in some L2 by
// prep's zeroing (agent stores never invalidate L2 copies).
#define LDS_H_STRIDE  772    // shorts; 8B-aligned rows, low conflicts (R9-measured)
#define LDS_T0_STRIDE 1540   // shorts
#define XCH_STRIDE    17     // 16 + 1 pad floats

#define LDW8(n0,n1,n2,n3,n4,n5,n6,n7, p) \
    asm volatile("global_load_dwordx4 %0, %8, off\n\t" \
                 "global_load_dwordx4 %1, %8, off offset:64\n\t" \
                 "global_load_dwordx4 %2, %8, off offset:128\n\t" \
                 "global_load_dwordx4 %3, %8, off offset:192\n\t" \
                 "global_load_dwordx4 %4, %8, off offset:256\n\t" \
                 "global_load_dwordx4 %5, %8, off offset:320\n\t" \
                 "global_load_dwordx4 %6, %8, off offset:384\n\t" \
                 "global_load_dwordx4 %7, %8, off offset:448\n\t" \
                 "s_waitcnt vmcnt(0)" \
                 : "=&v"(n0),"=&v"(n1),"=&v"(n2),"=&v"(n3), \
                   "=&v"(n4),"=&v"(n5),"=&v"(n6),"=&v"(n7) \
                 : "v"(p))

// 6 batched agent-scope (sc1) 64B chunk loads for the folded proj, one wait.
#define LDA6(n0,n1,n2,n3,n4,n5, p) \
    asm volatile("global_load_dwordx4 %0, %6, off sc1\n\t" \
                 "global_load_dwordx4 %1, %6, off offset:64 sc1\n\t" \
                 "global_load_dwordx4 %2, %6, off offset:128 sc1\n\t" \
                 "global_load_dwordx4 %3, %6, off offset:192 sc1\n\t" \
                 "global_load_dwordx4 %4, %6, off offset:256 sc1\n\t" \
                 "global_load_dwordx4 %5, %6, off offset:320 sc1\n\t" \
                 "s_waitcnt vmcnt(0)" \
                 : "=&v"(n0),"=&v"(n1),"=&v"(n2),"=&v"(n3),"=&v"(n4),"=&v"(n5) \
                 : "v"(p))

#define KSTEP(nm, idx) { \
    short8 a_ = *(const short8*)(&lds_h[col * LDS_H_STRIDE + (idx) * 32 + quad * 8]); \
    acc = __builtin_amdgcn_mfma_f32_16x16x32_bf16(a_, nm, acc, 0, 0, 0); }

static __device__ __forceinline__ bool sig_ok(u64 x) {
    return (unsigned short)x && (unsigned short)(x >> 16) &&
           (unsigned short)(x >> 32) && (unsigned short)(x >> 48);
}

__global__ __launch_bounds__(768, 3) void lstm_persist(
    const __hip_bfloat16* __restrict__ Wc,    // 3072 x 768 bf16 (Wih+Whh)
    const __hip_bfloat16* __restrict__ Wcat,  // 3072 x 1536 bf16 [Wih|Whh]
    const float* __restrict__ bias,           // 3072
    const float* __restrict__ c0in,           // B x H fp32
    const __hip_bfloat16* __restrict__ A0,    // 256 x 1536 [x0|h0]
    unsigned* sig,                            // T x B x 384 u32 (~bf16 pairs), zeroed
    const __hip_bfloat16* __restrict__ Wp,    // 80 x H padded bf16
    const float* __restrict__ bpost,          // 72
    float* __restrict__ out)                  // B x T x 72
{
    const int mtg  = blockIdx.x >> 4;    // batch group 0..15 (16 batches)
    const int jg   = blockIdx.x & 15;    // j group 0..15 (48 j values)
    const int tid  = threadIdx.x;
    const int lane = tid & 63;
    const int wave = tid >> 6;           // 0..11
    const int col  = lane & 15;
    const int quad = lane >> 4;
    const int jt_l = wave >> 2;          // 0..2  local j-tile
    const int gate = wave & 3;           // 0..3  (i,f,g,o)
    const int j    = jg * 48 + jt_l * 16 + col;   // this wave's j column

    __shared__ short lds_h[16 * LDS_T0_STRIDE];   // 49280 B (t0 tile; t>=1 stride 772)
    __shared__ float xch[12 * 16 * XCH_STRIDE];   // 13056 B gate exchange

    // ---- pin resident weight slice (Wc) in regs: 24 x short8 (sound asm) ----
    const short* wptr = (const short*)Wc + (size_t)(gate * H + j) * H + quad * 8;
    short8 w00,w01,w02,w03,w04,w05,w06,w07,w08,w09,w10,w11,
           w12,w13,w14,w15,w16,w17,w18,w19,w20,w21,w22,w23;
    LDW8(w00,w01,w02,w03,w04,w05,w06,w07, wptr);
    LDW8(w08,w09,w10,w11,w12,w13,w14,w15, wptr + 256);
    LDW8(w16,w17,w18,w19,w20,w21,w22,w23, wptr + 512);

    // ---- cell-role state (threads 0..383: two adjacent-j cells each) ----
    const int p    = tid;                 // pair id if < 384 (waves 0..5)
    const int bb   = p / 24;              // local batch 0..15
    const int jp   = p % 24;
    const int jloc = jp * 2;              // local j 0..46 (even)
    const int cjt  = jloc >> 4;           // j-tile of the pair
    const int jcol = jloc & 15;
    const int bglob = mtg * 16 + bb;
    const int jglob = jg * 48 + jloc;
    float c0v = 0.f, c1v = 0.f;
    float bi0=0,bi1=0,bf0=0,bf1=0,bg0=0,bg1=0,bo0=0,bo1=0;
    if (p < 384) {
        c0v = c0in[(size_t)bglob * H + jglob];
        c1v = c0in[(size_t)bglob * H + jglob + 1];
        bi0 = bias[0*H + jglob]; bi1 = bias[0*H + jglob + 1];
        bf0 = bias[1*H + jglob]; bf1 = bias[1*H + jglob + 1];
        bg0 = bias[2*H + jglob]; bg1 = bias[2*H + jglob + 1];
        bo0 = bias[3*H + jglob]; bo1 = bias[3*H + jglob + 1];
    }

    const u64* sig64c = (const u64*)sig;
    const int r0  = tid / 192;    // staging row base 0..3
    const int wrd = tid % 192;    // u64 word within row

    for (int t = 0; t < T; ++t) {
        f32x4 acc = {0.f, 0.f, 0.f, 0.f};

        if (t == 0) {
            // ---- stage A0[16 rows][1536] -> LDS ----
            const u64* a8 = (const u64*)((const short*)A0 + (size_t)(mtg * 16) * 1536);
#pragma unroll
            for (int i = 0; i < 8; ++i) {
                int idx = tid + i * 768;      // 0..6143 (16 rows x 384 u64)
                int br  = idx / 384;
                int ch  = idx % 384;
                *(u64*)&lds_h[br * LDS_T0_STRIDE + ch * 4] = a8[(size_t)br * 384 + ch];
            }
            __syncthreads();   // (B)

            // ---- K=1536 GEMM streaming Wcat (one-time) ----
            const short* wq = (const short*)Wcat + (size_t)(gate * H + j) * 1536 + quad * 8;
            for (int kk = 0; kk < 48; ++kk) {
                short8 a_ = *(const short8*)(&lds_h[col * LDS_T0_STRIDE + kk * 32 + quad * 8]);
                short8 b_ = *(const short8*)(wq + kk * 32);
                acc = __builtin_amdgcn_mfma_f32_16x16x32_bf16(a_, b_, acc, 0, 0, 0);
            }
        } else {
            // ---- poll+stage h(t-1): 4 owned u64 words, BATCHED loads ----
            const u64* hb = sig64c + ((size_t)(t - 1) * B + (size_t)(mtg * 16)) * 192 + wrd;
            u64 x0 = __hip_atomic_load(hb + (size_t)(r0     ) * 192,
                                       __ATOMIC_RELAXED, __HIP_MEMORY_SCOPE_AGENT);
            u64 x1 = __hip_atomic_load(hb + (size_t)(r0 +  4) * 192,
                                       __ATOMIC_RELAXED, __HIP_MEMORY_SCOPE_AGENT);
            u64 x2 = __hip_atomic_load(hb + (size_t)(r0 +  8) * 192,
                                       __ATOMIC_RELAXED, __HIP_MEMORY_SCOPE_AGENT);
            u64 x3 = __hip_atomic_load(hb + (size_t)(r0 + 12) * 192,
                                       __ATOMIC_RELAXED, __HIP_MEMORY_SCOPE_AGENT);
            unsigned pending = 0xFu;
            if (sig_ok(x0)) { *(u64*)&lds_h[(r0     ) * LDS_H_STRIDE + wrd * 4] = ~x0; pending &= ~1u; }
            if (sig_ok(x1)) { *(u64*)&lds_h[(r0 +  4) * LDS_H_STRIDE + wrd * 4] = ~x1; pending &= ~2u; }
            if (sig_ok(x2)) { *(u64*)&lds_h[(r0 +  8) * LDS_H_STRIDE + wrd * 4] = ~x2; pending &= ~4u; }
            if (sig_ok(x3)) { *(u64*)&lds_h[(r0 + 12) * LDS_H_STRIDE + wrd * 4] = ~x3; pending &= ~8u; }
            int guard = 0;
            while (pending && ++guard < (1 << 22)) {
                __builtin_amdgcn_s_sleep(4);   // throttle: ~256 cyc between sweeps
                if (pending & 1u) x0 = __hip_atomic_load(hb + (size_t)(r0     ) * 192,
                                        __ATOMIC_RELAXED, __HIP_MEMORY_SCOPE_AGENT);
                if (pending & 2u) x1 = __hip_atomic_load(hb + (size_t)(r0 +  4) * 192,
                                        __ATOMIC_RELAXED, __HIP_MEMORY_SCOPE_AGENT);
                if (pending & 4u) x2 = __hip_atomic_load(hb + (size_t)(r0 +  8) * 192,
                                        __ATOMIC_RELAXED, __HIP_MEMORY_SCOPE_AGENT);
                if (pending & 8u) x3 = __hip_atomic_load(hb + (size_t)(r0 + 12) * 192,
                                        __ATOMIC_RELAXED, __HIP_MEMORY_SCOPE_AGENT);
                if ((pending & 1u) && sig_ok(x0)) { *(u64*)&lds_h[(r0     ) * LDS_H_STRIDE + wrd * 4] = ~x0; pending &= ~1u; }
                if ((pending & 2u) && sig_ok(x1)) { *(u64*)&lds_h[(r0 +  4) * LDS_H_STRIDE + wrd * 4] = ~x1; pending &= ~2u; }
                if ((pending & 4u) && sig_ok(x2)) { *(u64*)&lds_h[(r0 +  8) * LDS_H_STRIDE + wrd * 4] = ~x2; pending &= ~4u; }
                if ((pending & 8u) && sig_ok(x3)) { *(u64*)&lds_h[(r0 + 12) * LDS_H_STRIDE + wrd * 4] = ~x3; pending &= ~8u; }
            }
            __syncthreads();   // (B) lds_h ready

            // ---- K=768 GEMM vs pinned weights ----
            KSTEP(w00,0)  KSTEP(w01,1)  KSTEP(w02,2)  KSTEP(w03,3)
            KSTEP(w04,4)  KSTEP(w05,5)  KSTEP(w06,6)  KSTEP(w07,7)
            KSTEP(w08,8)  KSTEP(w09,9)  KSTEP(w10,10) KSTEP(w11,11)
            KSTEP(w12,12) KSTEP(w13,13) KSTEP(w14,14) KSTEP(w15,15)
            KSTEP(w16,16) KSTEP(w17,17) KSTEP(w18,18) KSTEP(w19,19)
            KSTEP(w20,20) KSTEP(w21,21) KSTEP(w22,22) KSTEP(w23,23)
        }

        // ---- exchange gate tiles through LDS ----
        float* xw = &xch[(size_t)wave * 16 * XCH_STRIDE];
#pragma unroll
        for (int r = 0; r < 4; ++r)
            xw[(quad * 4 + r) * XCH_STRIDE + col] = acc[r];
        __syncthreads();   // (C) xch ready; all lds_h reads of this step done

        // ---- cell update + inverted-bf16 publish (store IS the signal) ----
        if (p < 384) {
            const float* xg = &xch[(size_t)(cjt * 4) * 16 * XCH_STRIDE + bb * XCH_STRIDE + jcol];
            const int gs = 16 * XCH_STRIDE;
            float i0 = xg[0*gs] + bi0, i1 = xg[0*gs + 1] + bi1;
            float f0 = xg[1*gs] + bf0, f1 = xg[1*gs + 1] + bf1;
            float g0 = xg[2*gs] + bg0, g1 = xg[2*gs + 1] + bg1;
            float o0 = xg[3*gs] + bo0, o1 = xg[3*gs + 1] + bo1;
            float cn0 = sigm(f0) * c0v + sigm(i0) * tanh_fast(g0);
            float cn1 = sigm(f1) * c1v + sigm(i1) * tanh_fast(g1);
            c0v = cn0; c1v = cn1;
            __hip_bfloat16 h0b = __float2bfloat16(sigm(o0) * tanh_fast(cn0));
            __hip_bfloat16 h1b = __float2bfloat16(sigm(o1) * tanh_fast(cn1));
            unsigned lo = (unsigned)(unsigned short)~(*(unsigned short*)&h0b);  // nonzero
            unsigned hi = (unsigned)(unsigned short)~(*(unsigned short*)&h1b);  // nonzero
            __hip_atomic_store(&sig[((size_t)t * B + bglob) * 384 + (jglob >> 1)],
                               lo | (hi << 16),
                               __ATOMIC_RELAXED, __HIP_MEMORY_SCOPE_AGENT);
        }
        __syncthreads();   // (D) poll throttle: park all waves until publish done
    }

    // ---- R18a: stage tile t=99 into lds_h (one extra run of the proven poll) ----
    {
        const u64* hb = sig64c + ((size_t)(T - 1) * B + (size_t)(mtg * 16)) * 192 + wrd;
        u64 x0 = __hip_atomic_load(hb + (size_t)(r0     ) * 192,
                                   __ATOMIC_RELAXED, __HIP_MEMORY_SCOPE_AGENT);
        u64 x1 = __hip_atomic_load(hb + (size_t)(r0 +  4) * 192,
                                   __ATOMIC_RELAXED, __HIP_MEMORY_SCOPE_AGENT);
        u64 x2 = __hip_atomic_load(hb + (size_t)(r0 +  8) * 192,
                                   __ATOMIC_RELAXED, __HIP_MEMORY_SCOPE_AGENT);
        u64 x3 = __hip_atomic_load(hb + (size_t)(r0 + 12) * 192,
                                   __ATOMIC_RELAXED, __HIP_MEMORY_SCOPE_AGENT);
        unsigned pending = 0xFu;
        if (sig_ok(x0)) { *(u64*)&lds_h[(r0     ) * LDS_H_STRIDE + wrd * 4] = ~x0; pending &= ~1u; }
        if (sig_ok(x1)) { *(u64*)&lds_h[(r0 +  4) * LDS_H_STRIDE + wrd * 4] = ~x1; pending &= ~2u; }
        if (sig_ok(x2)) { *(u64*)&lds_h[(r0 +  8) * LDS_H_STRIDE + wrd * 4] = ~x2; pending &= ~4u; }
        if (sig_ok(x3)) { *(u64*)&lds_h[(r0 + 12) * LDS_H_STRIDE + wrd * 4] = ~x3; pending &= ~8u; }
        int guard = 0;
        while (pending && ++guard < (1 << 22)) {
            __builtin_amdgcn_s_sleep(4);
            if (pending & 1u) { x0 = __hip_atomic_load(hb + (size_t)(r0     ) * 192,
                                    __ATOMIC_RELAXED, __HIP_MEMORY_SCOPE_AGENT);
                if (sig_ok(x0)) { *(u64*)&lds_h[(r0     ) * LDS_H_STRIDE + wrd * 4] = ~x0; pending &= ~1u; } }
            if (pending & 2u) { x1 = __hip_atomic_load(hb + (size_t)(r0 +  4) * 192,
                                    __ATOMIC_RELAXED, __HIP_MEMORY_SCOPE_AGENT);
                if (sig_ok(x1)) { *(u64*)&lds_h[(r0 +  4) * LDS_H_STRIDE + wrd * 4] = ~x1; pending &= ~2u; } }
            if (pending & 4u) { x2 = __hip_atomic_load(hb + (size_t)(r0 +  8) * 192,
                                    __ATOMIC_RELAXED, __HIP_MEMORY_SCOPE_AGENT);
                if (sig_ok(x2)) { *(u64*)&lds_h[(r0 +  8) * LDS_H_STRIDE + wrd * 4] = ~x2; pending &= ~4u; } }
            if (pending & 8u) { x3 = __hip_atomic_load(hb + (size_t)(r0 + 12) * 192,
                                    __ATOMIC_RELAXED, __HIP_MEMORY_SCOPE_AGENT);
                if (sig_ok(x3)) { *(u64*)&lds_h[(r0 + 12) * LDS_H_STRIDE + wrd * 4] = ~x3; pending &= ~8u; } }
        }
        __syncthreads();   // lds_h = true-bit h(99) tile, whole block
    }

    // ---- R18b: folded projection. Group covers its 16 batch rows x 100 t:
    //      16 blocks x 12 waves = 192 waves >= 100 tiles (1 wave : 1 t).
    //      t<=98: sc1 global reads (visible-guaranteed). t==99: LDS reads. ----
    {
        const int wv = jg * 12 + wave;        // 0..191 unique within group
        if (wv < T) {
            const int t = wv;
            const short* Wb = (const short*)Wp;
            f32x4 pacc[5];
#pragma unroll
            for (int nt = 0; nt < 5; ++nt) pacc[nt] = (f32x4){0.f, 0.f, 0.f, 0.f};

            if (t == T - 1) {
                // tile 99 from LDS (true bits, no inversion)
                for (int kk = 0; kk < 24; ++kk) {
                    short8 a = *(const short8*)(&lds_h[col * LDS_H_STRIDE + kk * 32 + quad * 8]);
#pragma unroll
                    for (int nt = 0; nt < 5; ++nt) {
                        short8 b = *(const short8*)(Wb + (size_t)(nt * 16 + col) * H + quad * 8 + kk * 32);
                        pacc[nt] = __builtin_amdgcn_mfma_f32_16x16x32_bf16(a, b, pacc[nt], 0, 0, 0);
                    }
                }
            } else {
                // inverted bits from MALL via sc1; 6 chunks per waitcnt (pipelined RTs)
                const short* Ap = (const short*)sig + ((size_t)t * B + (size_t)(mtg * 16 + col)) * H + quad * 8;
#pragma unroll
                for (int g6 = 0; g6 < 4; ++g6) {
                    short8 a0, a1, a2, a3, a4, a5;
                    LDA6(a0, a1, a2, a3, a4, a5, Ap + g6 * 192);
                    const short* wk = Wb + (size_t)quad * 8 + (size_t)g6 * 192;
#pragma unroll
                    for (int nt = 0; nt < 5; ++nt) {
                        const short* wr = wk + (size_t)(nt * 16 + col) * H;
                        pacc[nt] = __builtin_amdgcn_mfma_f32_16x16x32_bf16(~a0, *(const short8*)(wr      ), pacc[nt], 0, 0, 0);
                        pacc[nt] = __builtin_amdgcn_mfma_f32_16x16x32_bf16(~a1, *(const short8*)(wr +  32), pacc[nt], 0, 0, 0);
                        pacc[nt] = __builtin_amdgcn_mfma_f32_16x16x32_bf16(~a2, *(const short8*)(wr +  64), pacc[nt], 0, 0, 0);
                        pacc[nt] = __builtin_amdgcn_mfma_f32_16x16x32_bf16(~a3, *(const short8*)(wr +  96), pacc[nt], 0, 0, 0);
                        pacc[nt] = __builtin_amdgcn_mfma_f32_16x16x32_bf16(~a4, *(const short8*)(wr + 128), pacc[nt], 0, 0, 0);
                        pacc[nt] = __builtin_amdgcn_mfma_f32_16x16x32_bf16(~a5, *(const short8*)(wr + 160), pacc[nt], 0, 0, 0);
                    }
                }
            }

#pragma unroll
            for (int nt = 0; nt < 5; ++nt) {
                const int o = nt * 16 + col;
                if (o < 72) {
                    const float bb2 = bpost[o];
#pragma unroll
                    for (int r = 0; r < 4; ++r) {
                        const int b = mtg * 16 + quad * 4 + r;
                        out[((size_t)b * T + t) * 72 + o] = pacc[nt][r] + bb2;
                    }
                }
            }
        }
    }
}

// ---------------- launch ----------------

extern "C" void kernel_launch(void* const* d_in, const int* in_sizes, int n_in,
                              void* d_out, int out_size, void* d_ws, size_t ws_size,
                              hipStream_t stream) {
    const float* src   = (const float*)d_in[0];
    const float* h0    = (const float*)d_in[2];
    const float* c0    = (const float*)d_in[3];
    const float* Wih   = (const float*)d_in[4];
    const float* Whh   = (const float*)d_in[5];
    const float* bih   = (const float*)d_in[6];
    const float* bhh   = (const float*)d_in[7];
    const float* Wpost = (const float*)d_in[8];
    const float* bpost = (const float*)d_in[9];
    float* out = (float*)d_out;

    char* ws = (char*)d_ws;
    __hip_bfloat16* Wcat = (__hip_bfloat16*)(ws + 0);          //  9,437,184 B
    __hip_bfloat16* Wc   = (__hip_bfloat16*)(ws + 9437184);    //  4,718,592 B
    float*          bias = (float*)(ws + 14155776);            //     12,288 B
    __hip_bfloat16* Wp   = (__hip_bfloat16*)(ws + 14168064);   //    122,880 B
    __hip_bfloat16* A0   = (__hip_bfloat16*)(ws + 14290944);   //    786,432 B
    unsigned*       sig  = (unsigned*)(ws + 15863808);         // 39,321,600 B

    // all prep (weights, Wp, A0, sig zero) in one dispatch
    prep_all<<<dim3(3, 9808), 256, 0, stream>>>(src, h0, Wih, Whh, bih, bhh, Wpost,
                                                Wc, Wcat, bias, Wp, A0, (u64*)sig);

    // steps 0..99 + folded projection in one persistent kernel (R14 core verbatim)
    lstm_persist<<<256, 768, 0, stream>>>(Wc, Wcat, bias, c0, A0, sig,
                                          Wp, bpost, out);
}

// Round 6
// 454.468 us; speedup vs baseline: 1.9801x; 1.0846x over previous
//
#include <hip/hip_runtime.h>
#include <hip/hip_bf16.h>
#include <math.h>

#define H 768
#define B 256
#define T 100

typedef __attribute__((ext_vector_type(8))) short short8;
typedef __attribute__((ext_vector_type(4))) float f32x4;
typedef __attribute__((ext_vector_type(4))) unsigned short us4;
typedef unsigned long long u64;

static __device__ __forceinline__ float sigm(float x) {
    return 1.0f / (1.0f + __expf(-x));
}
static __device__ __forceinline__ float tanh_fast(float x) {
    return 1.0f - 2.0f / (__expf(2.0f * x) + 1.0f);
}
static __device__ __forceinline__ unsigned short bf16b(float x) {
    __hip_bfloat16 h = __float2bfloat16(x);
    return *(unsigned short*)&h;
}

// ---------------- fused prep, R19 vectorized (single dispatch) ----------------
// Old prep was scalar (1 float/thread, 2B stores, 29424 blocks) and cost
// ~75us for ~72MB of traffic (~12-15us ideal). New layout, 5808 x 256:
//   bid <  2400 : sig zero   (block: 16KB via 4 x 16B stores/thread)
//   bid <  5472 : weight row y=bid-2400 (tid<192: float4 x2 loads,
//                 us4 stores to Wc + Wcat; tid==0: bias)
//   bid <  5552 : Wp row r=bid-5472 (zero-padded beyond 72)
//   bid <  5808 : A0 batch row b=bid-5552  [x0|h0]
__global__ __launch_bounds__(256) void prep_all(
        const float* __restrict__ src, const float* __restrict__ h0,
        const float* __restrict__ Wih, const float* __restrict__ Whh,
        const float* __restrict__ bih, const float* __restrict__ bhh,
        const float* __restrict__ Wpost,
        __hip_bfloat16* __restrict__ Wc,    // 3072 x 768 (Wih+Whh)
        __hip_bfloat16* __restrict__ Wcat,  // 3072 x 1536 [Wih|Whh]
        float* __restrict__ bias,           // 3072
        __hip_bfloat16* __restrict__ Wp,    // 80 x 768
        __hip_bfloat16* __restrict__ A0,    // 256 x 1536 [x0|h0]
        u64* __restrict__ sig64)            // T*B*192 u64, zeroed
{
    const int bid = blockIdx.x;
    const int tid = threadIdx.x;

    if (bid < 2400) {
        // ---- zero 39,321,600 B of sig: block chunk 16384 B ----
        char* bz = (char*)sig64 + (size_t)bid * 16384;
        const f32x4 z = {0.f, 0.f, 0.f, 0.f};
#pragma unroll
        for (int jj = 0; jj < 4; ++jj)
            *(f32x4*)(bz + (size_t)jj * 4096 + (size_t)tid * 16) = z;
    } else if (bid < 5472) {
        const int y = bid - 2400;
        if (tid < 192) {
            const int k4 = tid * 4;
            f32x4 a = *(const f32x4*)(Wih + (size_t)y * H + k4);
            f32x4 b = *(const f32x4*)(Whh + (size_t)y * H + k4);
            us4 wc, wa, wb;
#pragma unroll
            for (int i = 0; i < 4; ++i) {
                wc[i] = bf16b(a[i] + b[i]);
                wa[i] = bf16b(a[i]);
                wb[i] = bf16b(b[i]);
            }
            unsigned short* WcS   = (unsigned short*)Wc;
            unsigned short* WcatS = (unsigned short*)Wcat;
            *(us4*)(WcS   + (size_t)y * 768  + k4)       = wc;
            *(us4*)(WcatS + (size_t)y * 1536 + k4)       = wa;
            *(us4*)(WcatS + (size_t)y * 1536 + 768 + k4) = wb;
        }
        if (tid == 0) bias[y] = bih[y] + bhh[y];
    } else if (bid < 5552) {
        const int r = bid - 5472;
        if (tid < 192) {
            const int k4 = tid * 4;
            us4 w = {0, 0, 0, 0};
            if (r < 72) {
                f32x4 v = *(const f32x4*)(Wpost + (size_t)r * H + k4);
#pragma unroll
                for (int i = 0; i < 4; ++i) w[i] = bf16b(v[i]);
            }
            *(us4*)((unsigned short*)Wp + (size_t)r * 768 + k4) = w;
        }
    } else {
        const int b = bid - 5552;
        if (tid < 192) {
            const int k4 = tid * 4;
            f32x4 s = *(const f32x4*)(src + ((size_t)b * 16 + 15) * H + k4);
            f32x4 h = *(const f32x4*)(h0  + (size_t)b * H + k4);
            us4 ws, wh;
#pragma unroll
            for (int i = 0; i < 4; ++i) { ws[i] = bf16b(s[i]); wh[i] = bf16b(h[i]); }
            unsigned short* A0S = (unsigned short*)A0;
            *(us4*)(A0S + (size_t)b * 1536 + k4)       = ws;
            *(us4*)(A0S + (size_t)b * 1536 + 768 + k4) = wh;
        }
    }
}

// ---------------- persistent recurrence: steps 0..99 ----------------
// R14 core VERBATIM (proven 354us): 256 blocks (16 mtg x 16 jg) x 768 threads
// (12 waves = 3 jt x 4 gates), 1 gate/wave, 24 pinned short8, batched poll +
// (D) barrier throttle + s_sleep(4).
// Hard-won lessons (R15-R18), do not revisit:
//  - agent stores bypass ALL L2s incl. the producer's own; sc0 polls hit
//    stale lines forever (R16: FETCH down, dur +77%). MALL is the only
//    cross-block rendezvous on gfx950.
//  - poll-is-the-load beats flag-then-load (R17: +160us; release-flag
//    per step is catastrophic; gating on slowest producer serializes).
//  - folding proj into the tail forces sc1 uncached A-reads and serializes
//    behind the last step (R18: +60us vs standalone proj dispatch).
#define LDS_H_STRIDE  772    // shorts; 8B-aligned rows, low conflicts (R9-measured)
#define LDS_T0_STRIDE 1540   // shorts
#define XCH_STRIDE    17     // 16 + 1 pad floats

#define LDW8(n0,n1,n2,n3,n4,n5,n6,n7, p) \
    asm volatile("global_load_dwordx4 %0, %8, off\n\t" \
                 "global_load_dwordx4 %1, %8, off offset:64\n\t" \
                 "global_load_dwordx4 %2, %8, off offset:128\n\t" \
                 "global_load_dwordx4 %3, %8, off offset:192\n\t" \
                 "global_load_dwordx4 %4, %8, off offset:256\n\t" \
                 "global_load_dwordx4 %5, %8, off offset:320\n\t" \
                 "global_load_dwordx4 %6, %8, off offset:384\n\t" \
                 "global_load_dwordx4 %7, %8, off offset:448\n\t" \
                 "s_waitcnt vmcnt(0)" \
                 : "=&v"(n0),"=&v"(n1),"=&v"(n2),"=&v"(n3), \
                   "=&v"(n4),"=&v"(n5),"=&v"(n6),"=&v"(n7) \
                 : "v"(p))

#define KSTEP(nm, idx) { \
    short8 a_ = *(const short8*)(&lds_h[col * LDS_H_STRIDE + (idx) * 32 + quad * 8]); \
    acc = __builtin_amdgcn_mfma_f32_16x16x32_bf16(a_, nm, acc, 0, 0, 0); }

static __device__ __forceinline__ bool sig_ok(u64 x) {
    return (unsigned short)x && (unsigned short)(x >> 16) &&
           (unsigned short)(x >> 32) && (unsigned short)(x >> 48);
}

__global__ __launch_bounds__(768, 3) void lstm_persist(
    const __hip_bfloat16* __restrict__ Wc,    // 3072 x 768 bf16 (Wih+Whh)
    const __hip_bfloat16* __restrict__ Wcat,  // 3072 x 1536 bf16 [Wih|Whh]
    const float* __restrict__ bias,           // 3072
    const float* __restrict__ c0in,           // B x H fp32
    const __hip_bfloat16* __restrict__ A0,    // 256 x 1536 [x0|h0]
    unsigned* sig)                            // T x B x 384 u32 (~bf16 pairs), zeroed
{
    const int mtg  = blockIdx.x >> 4;    // batch group 0..15 (16 batches)
    const int jg   = blockIdx.x & 15;    // j group 0..15 (48 j values)
    const int tid  = threadIdx.x;
    const int lane = tid & 63;
    const int wave = tid >> 6;           // 0..11
    const int col  = lane & 15;
    const int quad = lane >> 4;
    const int jt_l = wave >> 2;          // 0..2  local j-tile
    const int gate = wave & 3;           // 0..3  (i,f,g,o)
    const int j    = jg * 48 + jt_l * 16 + col;   // this wave's j column

    __shared__ short lds_h[16 * LDS_T0_STRIDE];   // 49280 B (t0 tile; t>=1 stride 772)
    __shared__ float xch[12 * 16 * XCH_STRIDE];   // 13056 B gate exchange

    // ---- pin resident weight slice (Wc) in regs: 24 x short8 (sound asm) ----
    const short* wptr = (const short*)Wc + (size_t)(gate * H + j) * H + quad * 8;
    short8 w00,w01,w02,w03,w04,w05,w06,w07,w08,w09,w10,w11,
           w12,w13,w14,w15,w16,w17,w18,w19,w20,w21,w22,w23;
    LDW8(w00,w01,w02,w03,w04,w05,w06,w07, wptr);
    LDW8(w08,w09,w10,w11,w12,w13,w14,w15, wptr + 256);
    LDW8(w16,w17,w18,w19,w20,w21,w22,w23, wptr + 512);

    // ---- cell-role state (threads 0..383: two adjacent-j cells each) ----
    const int p    = tid;                 // pair id if < 384 (waves 0..5)
    const int bb   = p / 24;              // local batch 0..15
    const int jp   = p % 24;
    const int jloc = jp * 2;              // local j 0..46 (even)
    const int cjt  = jloc >> 4;           // j-tile of the pair
    const int jcol = jloc & 15;
    const int bglob = mtg * 16 + bb;
    const int jglob = jg * 48 + jloc;
    float c0v = 0.f, c1v = 0.f;
    float bi0=0,bi1=0,bf0=0,bf1=0,bg0=0,bg1=0,bo0=0,bo1=0;
    if (p < 384) {
        c0v = c0in[(size_t)bglob * H + jglob];
        c1v = c0in[(size_t)bglob * H + jglob + 1];
        bi0 = bias[0*H + jglob]; bi1 = bias[0*H + jglob + 1];
        bf0 = bias[1*H + jglob]; bf1 = bias[1*H + jglob + 1];
        bg0 = bias[2*H + jglob]; bg1 = bias[2*H + jglob + 1];
        bo0 = bias[3*H + jglob]; bo1 = bias[3*H + jglob + 1];
    }

    const u64* sig64c = (const u64*)sig;
    const int r0  = tid / 192;    // staging row base 0..3
    const int wrd = tid % 192;    // u64 word within row

    for (int t = 0; t < T; ++t) {
        f32x4 acc = {0.f, 0.f, 0.f, 0.f};

        if (t == 0) {
            // ---- stage A0[16 rows][1536] -> LDS (plain loads) ----
            const u64* a8 = (const u64*)((const short*)A0 + (size_t)(mtg * 16) * 1536);
#pragma unroll
            for (int i = 0; i < 8; ++i) {
                int idx = tid + i * 768;      // 0..6143 (16 rows x 384 u64)
                int br  = idx / 384;
                int ch  = idx % 384;
                *(u64*)&lds_h[br * LDS_T0_STRIDE + ch * 4] = a8[(size_t)br * 384 + ch];
            }
            __syncthreads();   // (B)

            // ---- K=1536 GEMM streaming Wcat (one-time) ----
            const short* wq = (const short*)Wcat + (size_t)(gate * H + j) * 1536 + quad * 8;
            for (int kk = 0; kk < 48; ++kk) {
                short8 a_ = *(const short8*)(&lds_h[col * LDS_T0_STRIDE + kk * 32 + quad * 8]);
                short8 b_ = *(const short8*)(wq + kk * 32);
                acc = __builtin_amdgcn_mfma_f32_16x16x32_bf16(a_, b_, acc, 0, 0, 0);
            }
        } else {
            // ---- poll+stage h(t-1): 4 owned u64 words, BATCHED loads ----
            const u64* hb = sig64c + ((size_t)(t - 1) * B + (size_t)(mtg * 16)) * 192 + wrd;
            u64 x0 = __hip_atomic_load(hb + (size_t)(r0     ) * 192,
                                       __ATOMIC_RELAXED, __HIP_MEMORY_SCOPE_AGENT);
            u64 x1 = __hip_atomic_load(hb + (size_t)(r0 +  4) * 192,
                                       __ATOMIC_RELAXED, __HIP_MEMORY_SCOPE_AGENT);
            u64 x2 = __hip_atomic_load(hb + (size_t)(r0 +  8) * 192,
                                       __ATOMIC_RELAXED, __HIP_MEMORY_SCOPE_AGENT);
            u64 x3 = __hip_atomic_load(hb + (size_t)(r0 + 12) * 192,
                                       __ATOMIC_RELAXED, __HIP_MEMORY_SCOPE_AGENT);
            unsigned pending = 0xFu;
            if (sig_ok(x0)) { *(u64*)&lds_h[(r0     ) * LDS_H_STRIDE + wrd * 4] = ~x0; pending &= ~1u; }
            if (sig_ok(x1)) { *(u64*)&lds_h[(r0 +  4) * LDS_H_STRIDE + wrd * 4] = ~x1; pending &= ~2u; }
            if (sig_ok(x2)) { *(u64*)&lds_h[(r0 +  8) * LDS_H_STRIDE + wrd * 4] = ~x2; pending &= ~4u; }
            if (sig_ok(x3)) { *(u64*)&lds_h[(r0 + 12) * LDS_H_STRIDE + wrd * 4] = ~x3; pending &= ~8u; }
            int guard = 0;
            while (pending && ++guard < (1 << 22)) {
                __builtin_amdgcn_s_sleep(4);   // throttle: ~256 cyc between sweeps
                if (pending & 1u) x0 = __hip_atomic_load(hb + (size_t)(r0     ) * 192,
                                        __ATOMIC_RELAXED, __HIP_MEMORY_SCOPE_AGENT);
                if (pending & 2u) x1 = __hip_atomic_load(hb + (size_t)(r0 +  4) * 192,
                                        __ATOMIC_RELAXED, __HIP_MEMORY_SCOPE_AGENT);
                if (pending & 4u) x2 = __hip_atomic_load(hb + (size_t)(r0 +  8) * 192,
                                        __ATOMIC_RELAXED, __HIP_MEMORY_SCOPE_AGENT);
                if (pending & 8u) x3 = __hip_atomic_load(hb + (size_t)(r0 + 12) * 192,
                                        __ATOMIC_RELAXED, __HIP_MEMORY_SCOPE_AGENT);
                if ((pending & 1u) && sig_ok(x0)) { *(u64*)&lds_h[(r0     ) * LDS_H_STRIDE + wrd * 4] = ~x0; pending &= ~1u; }
                if ((pending & 2u) && sig_ok(x1)) { *(u64*)&lds_h[(r0 +  4) * LDS_H_STRIDE + wrd * 4] = ~x1; pending &= ~2u; }
                if ((pending & 4u) && sig_ok(x2)) { *(u64*)&lds_h[(r0 +  8) * LDS_H_STRIDE + wrd * 4] = ~x2; pending &= ~4u; }
                if ((pending & 8u) && sig_ok(x3)) { *(u64*)&lds_h[(r0 + 12) * LDS_H_STRIDE + wrd * 4] = ~x3; pending &= ~8u; }
            }
            __syncthreads();   // (B) lds_h ready

            // ---- K=768 GEMM vs pinned weights ----
            KSTEP(w00,0)  KSTEP(w01,1)  KSTEP(w02,2)  KSTEP(w03,3)
            KSTEP(w04,4)  KSTEP(w05,5)  KSTEP(w06,6)  KSTEP(w07,7)
            KSTEP(w08,8)  KSTEP(w09,9)  KSTEP(w10,10) KSTEP(w11,11)
            KSTEP(w12,12) KSTEP(w13,13) KSTEP(w14,14) KSTEP(w15,15)
            KSTEP(w16,16) KSTEP(w17,17) KSTEP(w18,18) KSTEP(w19,19)
            KSTEP(w20,20) KSTEP(w21,21) KSTEP(w22,22) KSTEP(w23,23)
        }

        // ---- exchange gate tiles through LDS ----
        float* xw = &xch[(size_t)wave * 16 * XCH_STRIDE];
#pragma unroll
        for (int r = 0; r < 4; ++r)
            xw[(quad * 4 + r) * XCH_STRIDE + col] = acc[r];
        __syncthreads();   // (C) xch ready; all lds_h reads of this step done

        // ---- cell update + inverted-bf16 publish (store IS the signal) ----
        if (p < 384) {
            const float* xg = &xch[(size_t)(cjt * 4) * 16 * XCH_STRIDE + bb * XCH_STRIDE + jcol];
            const int gs = 16 * XCH_STRIDE;
            float i0 = xg[0*gs] + bi0, i1 = xg[0*gs + 1] + bi1;
            float f0 = xg[1*gs] + bf0, f1 = xg[1*gs + 1] + bf1;
            float g0 = xg[2*gs] + bg0, g1 = xg[2*gs + 1] + bg1;
            float o0 = xg[3*gs] + bo0, o1 = xg[3*gs + 1] + bo1;
            float cn0 = sigm(f0) * c0v + sigm(i0) * tanh_fast(g0);
            float cn1 = sigm(f1) * c1v + sigm(i1) * tanh_fast(g1);
            c0v = cn0; c1v = cn1;
            __hip_bfloat16 h0b = __float2bfloat16(sigm(o0) * tanh_fast(cn0));
            __hip_bfloat16 h1b = __float2bfloat16(sigm(o1) * tanh_fast(cn1));
            unsigned lo = (unsigned)(unsigned short)~(*(unsigned short*)&h0b);  // nonzero
            unsigned hi = (unsigned)(unsigned short)~(*(unsigned short*)&h1b);  // nonzero
            __hip_atomic_store(&sig[((size_t)t * B + bglob) * 384 + (jglob >> 1)],
                               lo | (hi << 16),
                               __ATOMIC_RELAXED, __HIP_MEMORY_SCOPE_AGENT);
        }
        __syncthreads();   // (D) poll throttle: park all waves until publish done
    }
}

// ---------------- post projection (reads inverted sig) ----------------
__global__ __launch_bounds__(64) void proj(
    const short* __restrict__ Hs,            // (T*B) x 768 inverted bf16
    const __hip_bfloat16* __restrict__ Wp,   // 80 x H (padded bf16)
    const float* __restrict__ bpost,         // 72
    float* __restrict__ out)                 // B x T x 72
{
    const int mt = blockIdx.x;
    const int lane = threadIdx.x;
    const int col = lane & 15;
    const int quad = lane >> 4;

    const short* Ap = Hs + (size_t)(mt * 16 + col) * H + quad * 8;
    const short* Wb = (const short*)Wp;

    f32x4 acc[5];
#pragma unroll
    for (int nt = 0; nt < 5; ++nt) acc[nt] = (f32x4){0.f, 0.f, 0.f, 0.f};

    for (int k = 0; k < H; k += 32) {
        short8 a = ~(*(const short8*)(Ap + k));   // un-invert
#pragma unroll
        for (int nt = 0; nt < 5; ++nt) {
            short8 b = *(const short8*)(Wb + (size_t)(nt * 16 + col) * H + quad * 8 + k);
            acc[nt] = __builtin_amdgcn_mfma_f32_16x16x32_bf16(a, b, acc[nt], 0, 0, 0);
        }
    }

#pragma unroll
    for (int nt = 0; nt < 5; ++nt) {
        const int o = nt * 16 + col;
        if (o < 72) {
            const float bb = bpost[o];
#pragma unroll
            for (int r = 0; r < 4; ++r) {
                const int m = mt * 16 + quad * 4 + r;
                const int t = m >> 8;        // row = t*256 + b
                const int b = m & 255;
                out[((size_t)b * T + t) * 72 + o] = acc[nt][r] + bb;
            }
        }
    }
}

// ---------------- launch ----------------

extern "C" void kernel_launch(void* const* d_in, const int* in_sizes, int n_in,
                              void* d_out, int out_size, void* d_ws, size_t ws_size,
                              hipStream_t stream) {
    const float* src   = (const float*)d_in[0];
    const float* h0    = (const float*)d_in[2];
    const float* c0    = (const float*)d_in[3];
    const float* Wih   = (const float*)d_in[4];
    const float* Whh   = (const float*)d_in[5];
    const float* bih   = (const float*)d_in[6];
    const float* bhh   = (const float*)d_in[7];
    const float* Wpost = (const float*)d_in[8];
    const float* bpost = (const float*)d_in[9];
    float* out = (float*)d_out;

    char* ws = (char*)d_ws;
    __hip_bfloat16* Wcat = (__hip_bfloat16*)(ws + 0);          //  9,437,184 B
    __hip_bfloat16* Wc   = (__hip_bfloat16*)(ws + 9437184);    //  4,718,592 B
    float*          bias = (float*)(ws + 14155776);            //     12,288 B
    __hip_bfloat16* Wp   = (__hip_bfloat16*)(ws + 14168064);   //    122,880 B
    __hip_bfloat16* A0   = (__hip_bfloat16*)(ws + 14290944);   //    786,432 B
    unsigned*       sig  = (unsigned*)(ws + 15863808);         // 39,321,600 B

    // all prep (sig zero, weights, Wp, A0) in one vectorized dispatch
    prep_all<<<5808, 256, 0, stream>>>(src, h0, Wih, Whh, bih, bhh, Wpost,
                                       Wc, Wcat, bias, Wp, A0, (u64*)sig);

    // steps 0..99 in one persistent kernel (R14 core verbatim, proven 354us)
    lstm_persist<<<256, 768, 0, stream>>>(Wc, Wcat, bias, c0, A0, sig);

    proj<<<1600, 64, 0, stream>>>((const short*)sig, Wp, bpost, out);
}